// Round 1
// baseline (1567.925 us; speedup 1.0000x reference)
//
#include <hip/hip_runtime.h>
#include <math.h>

#define NTOT 65536
#define KCB  2048
#define CDIM 256
#define HW   1024

#define OUT_LOSS 16777216
#define OUT_PERP 16777217
#define OUT_ENC  16777218

// workspace byte offsets
#define WS_SROW 0                       // 65536 float
#define WS_CK   262144                  // 2048 float
#define WS_IDX  270336                  // 65536 int
#define WS_CNT  532480                  // 2048 int
#define WS_PART 540672                  // 2048 double

__global__ __launch_bounds__(256) void k_zero_counts(int* __restrict__ cnt) {
    for (int i = threadIdx.x; i < KCB; i += 256) cnt[i] = 0;
}

// ck[k] = sum_c codebook[k][c]^2   (order-insensitive: enters d at magnitude 2e-5 vs ulp(256)=3e-5)
__global__ __launch_bounds__(256) void k_colnorm(const float* __restrict__ cb, float* __restrict__ ck) {
    int wave = threadIdx.x >> 6;
    int lane = threadIdx.x & 63;
    int r = blockIdx.x * 4 + wave;
    const float* row = cb + (size_t)r * CDIM;
    float4 v = *(const float4*)(row + lane * 4);
    float s = v.x*v.x + v.y*v.y + v.z*v.z + v.w*v.w;
    for (int off = 32; off >= 1; off >>= 1) s += __shfl_down(s, off, 64);
    if (lane == 0) ck[r] = s;
}

// srow[n] = sum_c z[b][c][hw]^2  (uniform-across-k shift: any order is argmin-safe)
__global__ __launch_bounds__(256) void k_rownorm(const float* __restrict__ z, float* __restrict__ srow) {
    int n = blockIdx.x * 256 + threadIdx.x;
    int b = n >> 10, hw = n & 1023;
    const float* base = z + (size_t)b * (CDIM * HW) + hw;
    float s = 0.f;
#pragma unroll 8
    for (int c = 0; c < CDIM; ++c) { float v = base[(size_t)c * HW]; s = fmaf(v, v, s); }
    srow[n] = s;
}

// fused fp32 distance GEMM + argmin. BN=128 n-rows x all K, k-tiles of 128, c-stages of 32.
#define BN   128
#define BKT  128
#define BC   32
#define LSTR 132   // +4 pad: breaks bank conflicts on transposed B stores

__global__ __launch_bounds__(256) void k_argmin(const float* __restrict__ z, const float* __restrict__ cb,
                                                const float* __restrict__ srow, const float* __restrict__ ckg,
                                                int* __restrict__ indices) {
    __shared__ float As[BC][LSTR];
    __shared__ float Bs[BC][LSTR];
    __shared__ float redD[16][BN];
    __shared__ int   redK[16][BN];

    const int tid = threadIdx.x;
    const int tx = tid & 15, ty = tid >> 4;
    const int n0 = blockIdx.x * BN;
    const int b = n0 >> 10;
    const int hw0 = n0 & 1023;
    const float* abase = z + (size_t)b * (CDIM * HW) + hw0;

    float sreg[8];
#pragma unroll
    for (int i = 0; i < 8; ++i) sreg[i] = srow[n0 + tx * 8 + i];

    float bestd[8]; int bestk[8];
#pragma unroll
    for (int i = 0; i < 8; ++i) { bestd[i] = INFINITY; bestk[i] = 0; }

    for (int k0 = 0; k0 < KCB; k0 += BKT) {
        float acc[8][8];
#pragma unroll
        for (int i = 0; i < 8; ++i)
#pragma unroll
            for (int j = 0; j < 8; ++j) acc[i][j] = 0.f;

        for (int c0 = 0; c0 < CDIM; c0 += BC) {
            __syncthreads();
            // stage A: As[c][n] = z[b][c0+c][hw0+n], coalesced float4 along n
#pragma unroll
            for (int l = 0; l < 4; ++l) {
                int i = tid + l * 256;
                int c = i >> 5;
                int n4 = (i & 31) << 2;
                float4 v = *(const float4*)(abase + (size_t)(c0 + c) * HW + n4);
                *(float4*)&As[c][n4] = v;
            }
            // stage B: Bs[c][k] = cb[k0+k][c0+c], float4 along c, transposed scalar stores
            const float* bbase = cb + (size_t)k0 * CDIM + c0;
#pragma unroll
            for (int l = 0; l < 4; ++l) {
                int i = tid + l * 256;
                int k = i >> 3;
                int c4 = (i & 7) << 2;
                float4 v = *(const float4*)(bbase + (size_t)k * CDIM + c4);
                Bs[c4 + 0][k] = v.x; Bs[c4 + 1][k] = v.y; Bs[c4 + 2][k] = v.z; Bs[c4 + 3][k] = v.w;
            }
            __syncthreads();
#pragma unroll 4
            for (int c = 0; c < BC; ++c) {
                float4 a0 = *(const float4*)&As[c][tx * 8];
                float4 a1 = *(const float4*)&As[c][tx * 8 + 4];
                float4 b0 = *(const float4*)&Bs[c][ty * 8];
                float4 b1 = *(const float4*)&Bs[c][ty * 8 + 4];
                float av[8] = {a0.x, a0.y, a0.z, a0.w, a1.x, a1.y, a1.z, a1.w};
                float bv[8] = {b0.x, b0.y, b0.z, b0.w, b1.x, b1.y, b1.z, b1.w};
#pragma unroll
                for (int i = 0; i < 8; ++i)
#pragma unroll
                    for (int j = 0; j < 8; ++j)
                        acc[i][j] = fmaf(av[i], bv[j], acc[i][j]);
            }
        }
        // epilogue: d = fl(fl(s - 2m) + ck)   (2m exact => fma contraction bitwise-safe)
        float ckr[8];
#pragma unroll
        for (int j = 0; j < 8; ++j) ckr[j] = ckg[k0 + ty * 8 + j];
#pragma unroll
        for (int i = 0; i < 8; ++i) {
            float s = sreg[i];
#pragma unroll
            for (int j = 0; j < 8; ++j) {
                float v = s - 2.0f * acc[i][j];
                float dd = v + ckr[j];
                if (dd < bestd[i]) { bestd[i] = dd; bestk[i] = k0 + ty * 8 + j; }  // strict <: first-min wins (k ascending per thread)
            }
        }
    }
    __syncthreads();
#pragma unroll
    for (int i = 0; i < 8; ++i) { redD[ty][tx * 8 + i] = bestd[i]; redK[ty][tx * 8 + i] = bestk[i]; }
    __syncthreads();
    if (tid < BN) {
        float bd = redD[0][tid]; int bk = redK[0][tid];
        for (int t = 1; t < 16; ++t) {
            float d = redD[t][tid]; int k = redK[t][tid];
            if (d < bd || (d == bd && k < bk)) { bd = d; bk = k; }  // cross-thread tie: lowest k (np.argmin)
        }
        indices[n0 + tid] = bk;
    }
}

// z_q_st = fl(z_e + fl(z_q - z_e)); accumulate fp64 MSE partials per block (contention-free)
__global__ __launch_bounds__(256) void k_gather(const float* __restrict__ z, const float* __restrict__ cb,
                                                const int* __restrict__ idx, float* __restrict__ out0,
                                                double* __restrict__ part) {
    __shared__ double sh[256];
    double acc = 0.0;
    size_t base = (size_t)blockIdx.x * 8192;
    for (int i = 0; i < 32; ++i) {
        size_t e = base + (size_t)i * 256 + threadIdx.x;
        int hw = (int)(e & 1023);
        size_t t = e >> 10;
        int c = (int)(t & 255);
        int b = (int)(t >> 8);
        int n = (b << 10) | hw;
        int k = idx[n];
        float q = cb[(size_t)k * CDIM + c];
        float ze = z[e];
        float d = q - ze;
        out0[e] = ze + d;
        acc += (double)d * (double)d;
    }
    sh[threadIdx.x] = acc;
    __syncthreads();
    for (int s = 128; s > 0; s >>= 1) {
        if (threadIdx.x < s) sh[threadIdx.x] += sh[threadIdx.x + s];
        __syncthreads();
    }
    if (threadIdx.x == 0) part[blockIdx.x] = sh[0];
}

// zero the 536MB encodings region (float2: region byte-offset is 8-aligned, not 16)
__global__ __launch_bounds__(256) void k_zero_enc(float2* __restrict__ enc) {
    size_t base = (size_t)blockIdx.x * (256 * 32) + threadIdx.x;
#pragma unroll
    for (int i = 0; i < 32; ++i) enc[base + (size_t)i * 256] = make_float2(0.f, 0.f);
}

__global__ __launch_bounds__(256) void k_scatter(const int* __restrict__ idx, float* __restrict__ enc,
                                                 int* __restrict__ cnt) {
    int n = blockIdx.x * 256 + threadIdx.x;
    int k = idx[n];
    enc[(size_t)n * KCB + k] = 1.0f;
    atomicAdd(&cnt[k], 1);
}

__global__ __launch_bounds__(256) void k_finalize(const double* __restrict__ part, const int* __restrict__ cnt,
                                                  float* __restrict__ out) {
    __shared__ double sh[256];
    double a = 0.0;
    for (int i = threadIdx.x; i < 2048; i += 256) a += part[i];
    sh[threadIdx.x] = a; __syncthreads();
    for (int s = 128; s > 0; s >>= 1) { if (threadIdx.x < s) sh[threadIdx.x] += sh[threadIdx.x + s]; __syncthreads(); }
    double total = sh[0];
    __syncthreads();
    double p = 0.0;
    for (int i = threadIdx.x; i < 2048; i += 256) {
        double pm = (double)cnt[i] / 65536.0;
        p += pm * log(pm + 1e-10);
    }
    sh[threadIdx.x] = p; __syncthreads();
    for (int s = 128; s > 0; s >>= 1) { if (threadIdx.x < s) sh[threadIdx.x] += sh[threadIdx.x + s]; __syncthreads(); }
    if (threadIdx.x == 0) {
        double mean = total / ((double)NTOT * (double)CDIM);
        out[OUT_LOSS] = (float)(mean * 1.25);   // codebook_loss + 0.25*commitment_loss, equal forward values
        out[OUT_PERP] = (float)exp(-sh[0]);
    }
}

extern "C" void kernel_launch(void* const* d_in, const int* in_sizes, int n_in,
                              void* d_out, int out_size, void* d_ws, size_t ws_size,
                              hipStream_t stream) {
    const float* z  = (const float*)d_in[0];
    const float* cb = (const float*)d_in[1];
    float* out = (float*)d_out;
    char* ws = (char*)d_ws;
    float*  srow = (float*)(ws + WS_SROW);
    float*  ck   = (float*)(ws + WS_CK);
    int*    idx  = (int*)(ws + WS_IDX);
    int*    cnt  = (int*)(ws + WS_CNT);
    double* part = (double*)(ws + WS_PART);

    hipLaunchKernelGGL(k_zero_counts, dim3(1),    dim3(256), 0, stream, cnt);
    hipLaunchKernelGGL(k_colnorm,     dim3(512),  dim3(256), 0, stream, cb, ck);
    hipLaunchKernelGGL(k_rownorm,     dim3(256),  dim3(256), 0, stream, z, srow);
    hipLaunchKernelGGL(k_argmin,      dim3(512),  dim3(256), 0, stream, z, cb, srow, ck, idx);
    hipLaunchKernelGGL(k_gather,      dim3(2048), dim3(256), 0, stream, z, cb, idx, out, part);
    hipLaunchKernelGGL(k_zero_enc,    dim3(8192), dim3(256), 0, stream, (float2*)(out + OUT_ENC));
    hipLaunchKernelGGL(k_scatter,     dim3(256),  dim3(256), 0, stream, idx, out + OUT_ENC, cnt);
    hipLaunchKernelGGL(k_finalize,    dim3(1),    dim3(256), 0, stream, part, cnt, out);
}

// Round 2
// 1102.553 us; speedup vs baseline: 1.4221x; 1.4221x over previous
//
#include <hip/hip_runtime.h>
#include <hip/hip_bf16.h>
#include <math.h>

#define NTOT 65536
#define KCB  2048
#define CDIM 256
#define HW   1024

#define OUT_LOSS 16777216
#define OUT_PERP 16777217
#define OUT_ENC  16777218

// bf16 staging lives in the (later overwritten) encodings output region:
#define ZB_OFF_F  16777232   // 64B-aligned; 33.5 MB zb [65536][256] bf16
#define CBB_OFF_F 33554448   // 1 MB cbb [2048][256] bf16

// workspace byte offsets
#define WS_SROW 0                       // 65536 float
#define WS_CK   262144                  // 2048 float
#define WS_IDX  270336                  // 65536 int
#define WS_CNT  532480                  // 2048 int
#define WS_PART 540672                  // 2048 double

#define MARGIN 3e-3f

typedef __attribute__((ext_vector_type(8))) short short8;
typedef __attribute__((ext_vector_type(4))) float f32x4;

__device__ inline void lds_min_u64(unsigned long long* p, unsigned long long v) {
    unsigned long long old = *p;
    while (v < old) {
        unsigned long long assumed = old;
        old = atomicCAS(p, assumed, v);
        if (old == assumed) break;
    }
}

__global__ __launch_bounds__(256) void k_zero_counts(int* __restrict__ cnt) {
    for (int i = threadIdx.x; i < KCB; i += 256) cnt[i] = 0;
}

__global__ __launch_bounds__(256) void k_colnorm(const float* __restrict__ cb, float* __restrict__ ck) {
    int wave = threadIdx.x >> 6;
    int lane = threadIdx.x & 63;
    int r = blockIdx.x * 4 + wave;
    const float* row = cb + (size_t)r * CDIM;
    float4 v = *(const float4*)(row + lane * 4);
    float s = v.x*v.x + v.y*v.y + v.z*v.z + v.w*v.w;
    for (int off = 32; off >= 1; off >>= 1) s += __shfl_down(s, off, 64);
    if (lane == 0) ck[r] = s;
}

// srow: EXACT order as validated in round 1 (sequential fma c=0..255)
__global__ __launch_bounds__(256) void k_rownorm(const float* __restrict__ z, float* __restrict__ srow) {
    int n = blockIdx.x * 256 + threadIdx.x;
    int b = n >> 10, hw = n & 1023;
    const float* base = z + (size_t)b * (CDIM * HW) + hw;
    float s = 0.f;
#pragma unroll 8
    for (int c = 0; c < CDIM; ++c) { float v = base[(size_t)c * HW]; s = fmaf(v, v, s); }
    srow[n] = s;
}

// codebook fp32 -> bf16 (RNE)
__global__ __launch_bounds__(256) void k_prep_cb(const float* __restrict__ cb, ushort* __restrict__ cbb) {
    int t = blockIdx.x * 256 + threadIdx.x;   // 131072 threads x 4 elems
    float4 v = *(const float4*)(cb + (size_t)t * 4);
    ushort4 o;
    __hip_bfloat16 h;
    h = __float2bfloat16(v.x); o.x = *(ushort*)&h;
    h = __float2bfloat16(v.y); o.y = *(ushort*)&h;
    h = __float2bfloat16(v.z); o.z = *(ushort*)&h;
    h = __float2bfloat16(v.w); o.w = *(ushort*)&h;
    *(ushort4*)(cbb + (size_t)t * 4) = o;
}

// z [b][c][hw] fp32 -> zb [n][c] bf16 via LDS transpose; n = b*1024+hw
__global__ __launch_bounds__(256) void k_prep_z(const float* __restrict__ z, ushort* __restrict__ zb) {
    __shared__ float tile[64][65];
    int tid = threadIdx.x;
    int bid = blockIdx.x;
    int hwT = bid & 15, cT = (bid >> 4) & 3, b = bid >> 6;
    int c0 = cT * 64, hw0 = hwT * 64;
    int w = tid >> 6, hw = tid & 63;
#pragma unroll
    for (int l = 0; l < 16; ++l) {
        int c = l * 4 + w;
        tile[c][hw] = z[((size_t)b * CDIM + (c0 + c)) * HW + hw0 + hw];
    }
    __syncthreads();
    int r = tid >> 2, g = tid & 3;
    union { ushort u[16]; int4 v[2]; } pk;
#pragma unroll
    for (int j = 0; j < 16; ++j) {
        __hip_bfloat16 h = __float2bfloat16(tile[g * 16 + j][r]);
        pk.u[j] = *(ushort*)&h;
    }
    size_t n = (size_t)b * HW + hw0 + r;
    ushort* dst = zb + n * CDIM + c0 + g * 16;
    *(int4*)(dst) = pk.v[0];
    *(int4*)(dst + 8) = pk.v[1];
}

// ---- MFMA bf16 prefilter (2 passes) + exact fp32 rescore ----
// block: 64 rows x all K. 4 waves each own a 32-k quarter per 128-k iter.
// A-frags (64 rows x 256 c) held in VGPRs across both phases.
__global__ __launch_bounds__(256, 2) void k_mfma_argmin(
    const ushort* __restrict__ zb, const ushort* __restrict__ cbb,
    const float* __restrict__ z, const float* __restrict__ cb,
    const float* __restrict__ srow, const float* __restrict__ ckg,
    int* __restrict__ indices)
{
    __shared__ float rowmin4[4][64];
    __shared__ float rowminS[64];      // holds rowmin + MARGIN
    __shared__ int   cand[2048];
    __shared__ int   cnt;
    __shared__ unsigned long long best[64];

    const int tid = threadIdx.x;
    const int w = tid >> 6, lane = tid & 63;
    const int col = lane & 15, quad = lane >> 4;
    const int n0 = blockIdx.x * 64;

    // A fragments: areg[ntile][cstep], lane holds A[row=col][c=quad*8..+7]
    short8 areg[4][8];
#pragma unroll
    for (int nt = 0; nt < 4; ++nt)
#pragma unroll
        for (int cs = 0; cs < 8; ++cs)
            areg[nt][cs] = *(const short8*)(zb + ((size_t)(n0 + nt * 16 + col)) * CDIM + cs * 32 + quad * 8);

    float rmin[16];
#pragma unroll
    for (int s = 0; s < 16; ++s) rmin[s] = INFINITY;
    float thrv[16];
    if (tid == 0) cnt = 0;

    for (int phase = 0; phase < 2; ++phase) {
        for (int k0 = 0; k0 < KCB; k0 += 128) {
            const int kb = k0 + w * 32;
            f32x4 acc[4][2];
#pragma unroll
            for (int nt = 0; nt < 4; ++nt)
#pragma unroll
                for (int kt = 0; kt < 2; ++kt)
                    acc[nt][kt] = (f32x4){0.f, 0.f, 0.f, 0.f};
#pragma unroll
            for (int kt = 0; kt < 2; ++kt) {
                short8 bfrag[8];
#pragma unroll
                for (int cs = 0; cs < 8; ++cs)
                    bfrag[cs] = *(const short8*)(cbb + ((size_t)(kb + kt * 16 + col)) * CDIM + cs * 32 + quad * 8);
#pragma unroll
                for (int nt = 0; nt < 4; ++nt)
#pragma unroll
                    for (int cs = 0; cs < 8; ++cs)
                        acc[nt][kt] = __builtin_amdgcn_mfma_f32_16x16x32_bf16(areg[nt][cs], bfrag[cs], acc[nt][kt], 0, 0, 0);
            }
            // epilogue: d~ = -2*m~ + ck  (row-constant s omitted: argmin-invariant)
#pragma unroll
            for (int kt = 0; kt < 2; ++kt) {
                const int k = kb + kt * 16 + col;
                const float ckv = ckg[k];
#pragma unroll
                for (int nt = 0; nt < 4; ++nt)
#pragma unroll
                    for (int r = 0; r < 4; ++r) {
                        float dt = fmaf(-2.0f, acc[nt][kt][r], ckv);
                        const int s = nt * 4 + r;
                        if (phase == 0) {
                            rmin[s] = fminf(rmin[s], dt);
                        } else if (dt <= thrv[s]) {
                            int p = atomicAdd(&cnt, 1);
                            int row = nt * 16 + quad * 4 + r;
                            if (p < 2048) cand[p] = (row << 16) | k;
                        }
                    }
            }
        }
        if (phase == 0) {
            // reduce per-row min across the 16 col-lanes, then across waves
#pragma unroll
            for (int s = 0; s < 16; ++s) {
#pragma unroll
                for (int m = 1; m <= 8; m <<= 1)
                    rmin[s] = fminf(rmin[s], __shfl_xor(rmin[s], m, 64));
            }
            if (col == 0) {
#pragma unroll
                for (int s = 0; s < 16; ++s)
                    rowmin4[w][(s >> 2) * 16 + quad * 4 + (s & 3)] = rmin[s];
            }
            __syncthreads();
            if (tid < 64) {
                float v = fminf(fminf(rowmin4[0][tid], rowmin4[1][tid]),
                                fminf(rowmin4[2][tid], rowmin4[3][tid]));
                rowminS[tid] = v + MARGIN;
                best[tid] = ~0ull;
            }
            __syncthreads();
#pragma unroll
            for (int s = 0; s < 16; ++s)
                thrv[s] = rowminS[(s >> 2) * 16 + quad * 4 + (s & 3)];
        }
    }
    __syncthreads();

    // exact fp32 rescore of candidates: identical formula/order to the
    // round-1 kernel that matched numpy bit-for-bit.
    const int b = n0 >> 10, hw0 = n0 & 1023;
    const int nc = min(cnt, 2048);
    for (int t = tid; t < nc; t += 256) {
        const int rc = cand[t];
        const int row = rc >> 16, k = rc & 0xFFFF;
        const float* zp = z + (size_t)b * (CDIM * HW) + hw0 + row;
        const float* cp = cb + (size_t)k * CDIM;
        float m = 0.f;
#pragma unroll 8
        for (int c = 0; c < CDIM; ++c) m = fmaf(zp[(size_t)c << 10], cp[c], m);
        float d = (srow[n0 + row] - 2.0f * m) + ckg[k];   // 2m exact -> fma contraction bitwise-safe
        unsigned long long pk = ((unsigned long long)__float_as_uint(d) << 32) | (unsigned)k;
        lds_min_u64(&best[row], pk);   // d>0: bit-order == float order; low bits: lowest-k tie
    }
    __syncthreads();
    if (tid < 64) indices[n0 + tid] = (int)(best[tid] & 0xFFFFFFFFull);
}

// z_q_st = fl(z_e + fl(z_q - z_e)); fp64 MSE partials per block
__global__ __launch_bounds__(256) void k_gather(const float* __restrict__ z, const float* __restrict__ cb,
                                                const int* __restrict__ idx, float* __restrict__ out0,
                                                double* __restrict__ part) {
    __shared__ double sh[256];
    double acc = 0.0;
    size_t base = (size_t)blockIdx.x * 8192;
    for (int i = 0; i < 32; ++i) {
        size_t e = base + (size_t)i * 256 + threadIdx.x;
        int hw = (int)(e & 1023);
        size_t t = e >> 10;
        int c = (int)(t & 255);
        int b = (int)(t >> 8);
        int n = (b << 10) | hw;
        int k = idx[n];
        float q = cb[(size_t)k * CDIM + c];
        float ze = z[e];
        float d = q - ze;
        out0[e] = ze + d;
        acc += (double)d * (double)d;
    }
    sh[threadIdx.x] = acc;
    __syncthreads();
    for (int s = 128; s > 0; s >>= 1) {
        if (threadIdx.x < s) sh[threadIdx.x] += sh[threadIdx.x + s];
        __syncthreads();
    }
    if (threadIdx.x == 0) part[blockIdx.x] = sh[0];
}

// zero [OUT_LOSS, end): 16B-aligned float4 span (loss/perp rewritten by finalize after)
__global__ __launch_bounds__(256) void k_enc_zero(float4* __restrict__ p, float* __restrict__ tail) {
    size_t base = (size_t)blockIdx.x * (256 * 32) + threadIdx.x;
    float4 zv = make_float4(0.f, 0.f, 0.f, 0.f);
#pragma unroll
    for (int i = 0; i < 32; ++i) p[base + (size_t)i * 256] = zv;
    if (blockIdx.x == 0 && threadIdx.x == 0) { tail[0] = 0.f; tail[1] = 0.f; }
}

__global__ __launch_bounds__(256) void k_scatter(const int* __restrict__ idx, float* __restrict__ enc,
                                                 int* __restrict__ cnt) {
    int n = blockIdx.x * 256 + threadIdx.x;
    int k = idx[n];
    enc[(size_t)n * KCB + k] = 1.0f;
    atomicAdd(&cnt[k], 1);
}

__global__ __launch_bounds__(256) void k_finalize(const double* __restrict__ part, const int* __restrict__ cnt,
                                                  float* __restrict__ out) {
    __shared__ double sh[256];
    double a = 0.0;
    for (int i = threadIdx.x; i < 2048; i += 256) a += part[i];
    sh[threadIdx.x] = a; __syncthreads();
    for (int s = 128; s > 0; s >>= 1) { if (threadIdx.x < s) sh[threadIdx.x] += sh[threadIdx.x + s]; __syncthreads(); }
    double total = sh[0];
    __syncthreads();
    double p = 0.0;
    for (int i = threadIdx.x; i < 2048; i += 256) {
        double pm = (double)cnt[i] / 65536.0;
        p += pm * log(pm + 1e-10);
    }
    sh[threadIdx.x] = p; __syncthreads();
    for (int s = 128; s > 0; s >>= 1) { if (threadIdx.x < s) sh[threadIdx.x] += sh[threadIdx.x + s]; __syncthreads(); }
    if (threadIdx.x == 0) {
        double mean = total / ((double)NTOT * (double)CDIM);
        out[OUT_LOSS] = (float)(mean * 1.25);
        out[OUT_PERP] = (float)exp(-sh[0]);
    }
}

extern "C" void kernel_launch(void* const* d_in, const int* in_sizes, int n_in,
                              void* d_out, int out_size, void* d_ws, size_t ws_size,
                              hipStream_t stream) {
    const float* z  = (const float*)d_in[0];
    const float* cb = (const float*)d_in[1];
    float* out = (float*)d_out;
    char* ws = (char*)d_ws;
    float*  srow = (float*)(ws + WS_SROW);
    float*  ck   = (float*)(ws + WS_CK);
    int*    idx  = (int*)(ws + WS_IDX);
    int*    cnt  = (int*)(ws + WS_CNT);
    double* part = (double*)(ws + WS_PART);
    ushort* zb  = (ushort*)(out + ZB_OFF_F);
    ushort* cbb = (ushort*)(out + CBB_OFF_F);

    hipLaunchKernelGGL(k_zero_counts, dim3(1),    dim3(256), 0, stream, cnt);
    hipLaunchKernelGGL(k_prep_cb,     dim3(512),  dim3(256), 0, stream, cb, cbb);
    hipLaunchKernelGGL(k_colnorm,     dim3(512),  dim3(256), 0, stream, cb, ck);
    hipLaunchKernelGGL(k_rownorm,     dim3(256),  dim3(256), 0, stream, z, srow);
    hipLaunchKernelGGL(k_prep_z,      dim3(4096), dim3(256), 0, stream, z, zb);
    hipLaunchKernelGGL(k_mfma_argmin, dim3(1024), dim3(256), 0, stream, zb, cbb, z, cb, srow, ck, idx);
    hipLaunchKernelGGL(k_gather,      dim3(2048), dim3(256), 0, stream, z, cb, idx, out, part);
    hipLaunchKernelGGL(k_enc_zero,    dim3(4096), dim3(256), 0, stream, (float4*)(out + OUT_LOSS), out + (OUT_LOSS + (size_t)33554432 * 4));
    hipLaunchKernelGGL(k_scatter,     dim3(256),  dim3(256), 0, stream, idx, out + OUT_ENC, cnt);
    hipLaunchKernelGGL(k_finalize,    dim3(1),    dim3(256), 0, stream, part, cnt, out);
}

// Round 3
// 1003.775 us; speedup vs baseline: 1.5620x; 1.0984x over previous
//
#include <hip/hip_runtime.h>
#include <hip/hip_bf16.h>
#include <math.h>

#define NTOT 65536
#define KCB  2048
#define CDIM 256
#define HW   1024

#define OUT_LOSS 16777216
#define OUT_PERP 16777217
#define OUT_ENC  16777218

// bf16 staging lives in the (later overwritten) encodings output region:
#define ZB_OFF_F  16777232   // 64B-aligned; 33.5 MB zb [65536][256] bf16
#define CBB_OFF_F 33554448   // 1 MB cbb [2048][256] bf16

// workspace byte offsets
#define WS_SROW 0                       // 65536 float
#define WS_CK   262144                  // 2048 float
#define WS_IDX  270336                  // 65536 int
#define WS_CNT  532480                  // 2048 int
#define WS_PART 540672                  // 1024 double

#define MARGIN 3e-3f
#define CAP 4096

typedef __attribute__((ext_vector_type(8))) short short8;
typedef __attribute__((ext_vector_type(4))) float f32x4;

// order-preserving float<->uint key (handles negative d~)
__device__ inline unsigned enc_f(float x) {
    unsigned u = __float_as_uint(x);
    return (u & 0x80000000u) ? ~u : (u | 0x80000000u);
}
__device__ inline float dec_f(unsigned e) {
    unsigned u = (e & 0x80000000u) ? (e ^ 0x80000000u) : ~e;
    return __uint_as_float(u);
}

__device__ inline void lds_min_u64(unsigned long long* p, unsigned long long v) {
    unsigned long long old = *p;
    while (v < old) {
        unsigned long long assumed = old;
        old = atomicCAS(p, assumed, v);
        if (old == assumed) break;
    }
}

// codebook fp32 -> bf16 + row norms + zero histogram (one pass over cb)
__global__ __launch_bounds__(256) void k_prep_cb(const float* __restrict__ cb, ushort* __restrict__ cbb,
                                                 float* __restrict__ ck, int* __restrict__ cntK) {
    int wv = threadIdx.x >> 6, lane = threadIdx.x & 63;
    int r = blockIdx.x * 4 + wv;
    const float* row = cb + (size_t)r * CDIM;
    float4 v = *(const float4*)(row + lane * 4);
    ushort4 o;
    __hip_bfloat16 h;
    h = __float2bfloat16(v.x); o.x = *(ushort*)&h;
    h = __float2bfloat16(v.y); o.y = *(ushort*)&h;
    h = __float2bfloat16(v.z); o.z = *(ushort*)&h;
    h = __float2bfloat16(v.w); o.w = *(ushort*)&h;
    *(ushort4*)(cbb + (size_t)r * CDIM + lane * 4) = o;
    float s = v.x*v.x + v.y*v.y + v.z*v.z + v.w*v.w;
    for (int off = 32; off >= 1; off >>= 1) s += __shfl_down(s, off, 64);
    if (lane == 0) ck[r] = s;
    if (lane == 1) cntK[r] = 0;
}

// srow: EXACT order as validated in round 1 (sequential fma c=0..255)
__global__ __launch_bounds__(256) void k_rownorm(const float* __restrict__ z, float* __restrict__ srow) {
    int n = blockIdx.x * 256 + threadIdx.x;
    int b = n >> 10, hw = n & 1023;
    const float* base = z + (size_t)b * (CDIM * HW) + hw;
    float s = 0.f;
#pragma unroll 8
    for (int c = 0; c < CDIM; ++c) { float v = base[(size_t)c * HW]; s = fmaf(v, v, s); }
    srow[n] = s;
}

// z [b][c][hw] fp32 -> zb [n][c] bf16 via LDS transpose; n = b*1024+hw
__global__ __launch_bounds__(256) void k_prep_z(const float* __restrict__ z, ushort* __restrict__ zb) {
    __shared__ float tile[64][65];
    int tid = threadIdx.x;
    int bid = blockIdx.x;
    int hwT = bid & 15, cT = (bid >> 4) & 3, b = bid >> 6;
    int c0 = cT * 64, hw0 = hwT * 64;
    int w = tid >> 6, hw = tid & 63;
#pragma unroll
    for (int l = 0; l < 16; ++l) {
        int c = l * 4 + w;
        tile[c][hw] = z[((size_t)b * CDIM + (c0 + c)) * HW + hw0 + hw];
    }
    __syncthreads();
    int r = tid >> 2, g = tid & 3;
    union { ushort u[16]; int4 v[2]; } pk;
#pragma unroll
    for (int j = 0; j < 16; ++j) {
        __hip_bfloat16 h = __float2bfloat16(tile[g * 16 + j][r]);
        pk.u[j] = *(ushort*)&h;
    }
    size_t n = (size_t)b * HW + hw0 + r;
    ushort* dst = zb + n * CDIM + c0 + g * 16;
    *(int4*)(dst) = pk.v[0];
    *(int4*)(dst + 8) = pk.v[1];
}

// ---- single-pass MFMA bf16 prefilter with shared running threshold + exact rescore ----
__global__ __launch_bounds__(256, 2) void k_mfma_argmin(
    const ushort* __restrict__ zb, const ushort* __restrict__ cbb,
    const float* __restrict__ z, const float* __restrict__ cb,
    const float* __restrict__ srow, const float* __restrict__ ckg,
    int* __restrict__ indices, int* __restrict__ cntK)
{
    __shared__ unsigned rowminU[64];
    __shared__ int   candRK[CAP];
    __shared__ float candD[CAP];
    __shared__ int   cnt;
    __shared__ float thrF[64];
    __shared__ unsigned long long best[64];

    const int tid = threadIdx.x;
    const int w = tid >> 6, lane = tid & 63;
    const int col = lane & 15, quad = lane >> 4;
    const int n0 = blockIdx.x * 64;

    // A fragments: areg[ntile][cstep], lane holds A[row=col][c=quad*8..+7]
    short8 areg[4][8];
#pragma unroll
    for (int nt = 0; nt < 4; ++nt)
#pragma unroll
        for (int cs = 0; cs < 8; ++cs)
            areg[nt][cs] = *(const short8*)(zb + ((size_t)(n0 + nt * 16 + col)) * CDIM + cs * 32 + quad * 8);

    if (tid < 64) { rowminU[tid] = 0xFFFFFFFFu; best[tid] = ~0ull; }
    if (tid == 0) cnt = 0;

    float gmin[16];
#pragma unroll
    for (int s = 0; s < 16; ++s) gmin[s] = INFINITY;
    __syncthreads();

    int npass = 1;
    for (int pass = 0; pass < npass; ++pass) {
        for (int k0 = 0; k0 < KCB; k0 += 128) {
            const int kb = k0 + w * 32;
            f32x4 acc[4][2];
#pragma unroll
            for (int nt = 0; nt < 4; ++nt)
#pragma unroll
                for (int kt = 0; kt < 2; ++kt)
                    acc[nt][kt] = (f32x4){0.f, 0.f, 0.f, 0.f};
#pragma unroll
            for (int kt = 0; kt < 2; ++kt) {
                short8 bfrag[8];
#pragma unroll
                for (int cs = 0; cs < 8; ++cs)
                    bfrag[cs] = *(const short8*)(cbb + ((size_t)(kb + kt * 16 + col)) * CDIM + cs * 32 + quad * 8);
#pragma unroll
                for (int nt = 0; nt < 4; ++nt)
#pragma unroll
                    for (int cs = 0; cs < 8; ++cs)
                        acc[nt][kt] = __builtin_amdgcn_mfma_f32_16x16x32_bf16(areg[nt][cs], bfrag[cs], acc[nt][kt], 0, 0, 0);
            }
            // --- update phase: publish per-row mins (pass 0 only; monotone -> race-safe)
            if (pass == 0) {
#pragma unroll
                for (int kt = 0; kt < 2; ++kt) {
                    const float ckv = ckg[kb + kt * 16 + col];
#pragma unroll
                    for (int nt = 0; nt < 4; ++nt)
#pragma unroll
                        for (int r = 0; r < 4; ++r) {
                            float dt = fmaf(-2.0f, acc[nt][kt][r], ckv);
                            const int s = nt * 4 + r;
                            if (dt < gmin[s]) {
                                gmin[s] = dt;
                                atomicMin(&rowminU[nt * 16 + quad * 4 + r], enc_f(dt));
                            }
                        }
                }
            }
            __syncthreads();
            // --- collect phase: refresh from LDS (>= final min: superset-safe), then push
#pragma unroll
            for (int s = 0; s < 16; ++s) {
                int row = (s >> 2) * 16 + quad * 4 + (s & 3);
                gmin[s] = fminf(gmin[s], dec_f(rowminU[row]));
            }
#pragma unroll
            for (int kt = 0; kt < 2; ++kt) {
                const int k = kb + kt * 16 + col;
                const float ckv = ckg[k];
#pragma unroll
                for (int nt = 0; nt < 4; ++nt)
#pragma unroll
                    for (int r = 0; r < 4; ++r) {
                        float dt = fmaf(-2.0f, acc[nt][kt][r], ckv);
                        const int s = nt * 4 + r;
                        if (dt <= gmin[s] + MARGIN) {
                            int p = atomicAdd(&cnt, 1);
                            if (p < CAP) {
                                candRK[p] = ((nt * 16 + quad * 4 + r) << 16) | k;
                                candD[p] = dt;
                            }
                        }
                    }
            }
        }
        __syncthreads();
        if (pass == 0 && cnt > CAP) {   // overflow (expected never): redo collect with final thresholds
            npass = 2;
            if (tid == 0) cnt = 0;
            __syncthreads();
        }
    }
    const int nc = min(cnt, CAP);
    if (tid < 64) thrF[tid] = dec_f(rowminU[tid]) + MARGIN;
    __syncthreads();

    // exact fp32 rescore (identical formula/order to round-1 validated kernel)
    const int b = n0 >> 10, hw0 = n0 & 1023;
    for (int t = tid; t < nc; t += 256) {
        const int rc = candRK[t];
        const int row = rc >> 16, k = rc & 0xFFFF;
        if (candD[t] > thrF[row]) continue;
        const float* zp = z + (size_t)b * (CDIM * HW) + hw0 + row;
        const float* cp = cb + (size_t)k * CDIM;
        float m = 0.f;
#pragma unroll 8
        for (int c = 0; c < CDIM; ++c) m = fmaf(zp[(size_t)c << 10], cp[c], m);
        float d = (srow[n0 + row] - 2.0f * m) + ckg[k];   // 2m exact -> fma contraction bitwise-safe
        unsigned long long pk = ((unsigned long long)__float_as_uint(d) << 32) | (unsigned)k;
        lds_min_u64(&best[row], pk);   // d>=0: bit-order == float order; low bits: lowest-k tie
    }
    __syncthreads();
    if (tid < 64) {
        int bk = (int)(best[tid] & 0xFFFFFFFFull);
        indices[n0 + tid] = bk;
        atomicAdd(&cntK[bk], 1);
    }
}

// coalesced gather: block owns 64 rows; stage their codebook rows in LDS transposed
__global__ __launch_bounds__(256, 2) void k_gather(const float* __restrict__ z, const float* __restrict__ cb,
                                                   const int* __restrict__ idx, float* __restrict__ out0,
                                                   double* __restrict__ part) {
    __shared__ float qt[CDIM * 64];   // qt[c][n] 64 KB
    __shared__ double sh[256];
    const int tid = threadIdx.x;
    const int nl = tid & 63, cg = tid >> 6;
    const int n0 = blockIdx.x * 64;
    const int b = n0 >> 10, hw0 = n0 & 1023;
    const int k = idx[n0 + nl];
    const float* crow = cb + (size_t)k * CDIM + cg * 64;
#pragma unroll
    for (int j4 = 0; j4 < 16; ++j4) {
        float4 v = *(const float4*)(crow + j4 * 4);
        int c = cg * 64 + j4 * 4;
        qt[(c + 0) * 64 + nl] = v.x;
        qt[(c + 1) * 64 + nl] = v.y;
        qt[(c + 2) * 64 + nl] = v.z;
        qt[(c + 3) * 64 + nl] = v.w;
    }
    __syncthreads();
    double acc = 0.0;
    const size_t ebase = ((size_t)b * CDIM) * HW + hw0 + nl;
#pragma unroll 4
    for (int j = 0; j < 64; ++j) {
        int c = cg * 64 + j;
        size_t e = ebase + ((size_t)c << 10);
        float ze = z[e];
        float q = qt[c * 64 + nl];
        float d = q - ze;
        out0[e] = ze + d;
        acc += (double)d * (double)d;
    }
    sh[tid] = acc;
    __syncthreads();
    for (int s = 128; s > 0; s >>= 1) {
        if (tid < s) sh[tid] += sh[tid + s];
        __syncthreads();
    }
    if (tid == 0) part[blockIdx.x] = sh[0];
}

// fused zero + one-hot scatter over [OUT_LOSS, end) as float4 (16B-aligned anchor)
__global__ __launch_bounds__(256) void k_encodings(const int* __restrict__ idx, float4* __restrict__ p4,
                                                   float* __restrict__ tail) {
    __shared__ int sidx[17];
    const int tid = threadIdx.x;
    const size_t g0 = (size_t)blockIdx.x * 8192;
    const long f0 = 4L * (long)g0 - 2;
    int nlo = (int)(f0 >> 11); if (nlo < 0) nlo = 0;
    if (tid < 17) { int n = nlo + tid; sidx[tid] = (n < NTOT) ? idx[n] : -1; }
    __syncthreads();
    const float4 zv = make_float4(0.f, 0.f, 0.f, 0.f);
    for (int i = 0; i < 32; ++i) {
        size_t g = g0 + (size_t)i * 256 + tid;
        long fe = 4L * (long)g - 2;
        float4 v = zv;
        if (fe < 0) {
            // g==0: comps 0,1 = loss/perp (finalize rewrites), comps 2,3 = enc[n=0][k=0,1]
            int kk = sidx[0];
            if (kk == 0) v.z = 1.f;
            if (kk == 1) v.w = 1.f;
        } else {
            int n = (int)(fe >> 11);
            int k0c = (int)(fe & 2047);
            if (k0c >= 2045) {   // f4 straddles a row boundary
#pragma unroll
                for (int j = 0; j < 4; ++j) {
                    long fej = fe + j;
                    int nj = (int)(fej >> 11);
                    int kj = (int)(fej & 2047);
                    int li = nj - nlo;
                    int kk = (li >= 0 && li < 17) ? sidx[li] : -2;
                    ((float*)&v)[j] = (kk == kj) ? 1.f : 0.f;
                }
            } else {
                int d = sidx[n - nlo] - k0c;
                if (d >= 0 && d < 4) ((float*)&v)[d] = 1.f;
            }
        }
        p4[g] = v;
    }
    if (blockIdx.x == 0 && tid == 0) {
        // last 2 floats of out = enc[n=65535][k=2046,2047]
        int kk = idx[NTOT - 1];
        tail[0] = (kk == 2046) ? 1.f : 0.f;
        tail[1] = (kk == 2047) ? 1.f : 0.f;
    }
}

__global__ __launch_bounds__(256) void k_finalize(const double* __restrict__ part, const int* __restrict__ cnt,
                                                  float* __restrict__ out) {
    __shared__ double sh[256];
    double a = 0.0;
    for (int i = threadIdx.x; i < 1024; i += 256) a += part[i];
    sh[threadIdx.x] = a; __syncthreads();
    for (int s = 128; s > 0; s >>= 1) { if (threadIdx.x < s) sh[threadIdx.x] += sh[threadIdx.x + s]; __syncthreads(); }
    double total = sh[0];
    __syncthreads();
    double p = 0.0;
    for (int i = threadIdx.x; i < 2048; i += 256) {
        double pm = (double)cnt[i] / 65536.0;
        p += pm * log(pm + 1e-10);
    }
    sh[threadIdx.x] = p; __syncthreads();
    for (int s = 128; s > 0; s >>= 1) { if (threadIdx.x < s) sh[threadIdx.x] += sh[threadIdx.x + s]; __syncthreads(); }
    if (threadIdx.x == 0) {
        double mean = total / ((double)NTOT * (double)CDIM);
        out[OUT_LOSS] = (float)(mean * 1.25);
        out[OUT_PERP] = (float)exp(-sh[0]);
    }
}

extern "C" void kernel_launch(void* const* d_in, const int* in_sizes, int n_in,
                              void* d_out, int out_size, void* d_ws, size_t ws_size,
                              hipStream_t stream) {
    const float* z  = (const float*)d_in[0];
    const float* cb = (const float*)d_in[1];
    float* out = (float*)d_out;
    char* ws = (char*)d_ws;
    float*  srow = (float*)(ws + WS_SROW);
    float*  ck   = (float*)(ws + WS_CK);
    int*    idx  = (int*)(ws + WS_IDX);
    int*    cnt  = (int*)(ws + WS_CNT);
    double* part = (double*)(ws + WS_PART);
    ushort* zb  = (ushort*)(out + ZB_OFF_F);
    ushort* cbb = (ushort*)(out + CBB_OFF_F);

    hipLaunchKernelGGL(k_prep_cb,     dim3(512),  dim3(256), 0, stream, cb, cbb, ck, cnt);
    hipLaunchKernelGGL(k_rownorm,     dim3(256),  dim3(256), 0, stream, z, srow);
    hipLaunchKernelGGL(k_prep_z,      dim3(4096), dim3(256), 0, stream, z, zb);
    hipLaunchKernelGGL(k_mfma_argmin, dim3(1024), dim3(256), 0, stream, zb, cbb, z, cb, srow, ck, idx, cnt);
    hipLaunchKernelGGL(k_gather,      dim3(1024), dim3(256), 0, stream, z, cb, idx, out, part);
    hipLaunchKernelGGL(k_encodings,   dim3(4096), dim3(256), 0, stream, idx, (float4*)(out + OUT_LOSS),
                       out + (OUT_LOSS + (size_t)33554432 * 4));
    hipLaunchKernelGGL(k_finalize,    dim3(1),    dim3(256), 0, stream, part, cnt, out);
}